// Round 1
// baseline (1275.400 us; speedup 1.0000x reference)
//
#include <hip/hip_runtime.h>
#include <math.h>

#ifndef M_PI
#define M_PI 3.14159265358979323846
#endif

// Problem constants
#define BB 2
#define VV 180
#define RR 32
#define CC 512
#define NPIX 512
#define CH 12       // angles per LDS chunk in backprojection
#define NCHUNK 15   // 15 * 12 = 180

// ws layout (floats): [0,1024) h_ext (h duplicated, scaled by pi/V);
//                     [1024, 1024+360) trig (cos[180], sin[180]);
//                     [2048, ...) filt transposed [b][r][v][c]
#define FILT_OFF 2048

// ---------------------------------------------------------------------------
// Kernel A: compute ramp-filter impulse response h[k] = (1/N) sum ramp[m] cos(2pi m k/N)
// scaled by pi/V (folded backprojection scale), plus cos/sin angle tables.
// Integer mod-512 reduction keeps cosf args in [0, 2pi) -> full fp32 accuracy.
// ---------------------------------------------------------------------------
__global__ void precompute_kernel(float* __restrict__ ws) {
    int j = blockIdx.x * blockDim.x + threadIdx.x;  // 0..511
    if (j < 512) {
        float s = 0.f;
        for (int m = 1; m < 512; ++m) {             // m=0 term has ramp=0
            int p = (m * j) & 511;                  // exact (m*j) mod 512
            float ang = (float)(2.0 * M_PI / 512.0) * (float)p;
            int mm = m < 512 - m ? m : 512 - m;
            float ramp = 2.0f * (float)mm * (1.0f / 512.0f);
            s += ramp * cosf(ang);
        }
        s *= (1.0f / 512.0f);
        s *= (float)(M_PI / (double)VV);            // fold backprojection scale
        ws[j] = s;
        ws[j + 512] = s;                            // h_ext[j+512] == h[j]
    }
    if (j < VV) {
        float th = (float)((double)j * M_PI / 180.0);
        ws[1024 + j] = cosf(th);
        ws[1024 + 180 + j] = sinf(th);
    }
}

// ---------------------------------------------------------------------------
// Kernel B: circular convolution (ramp filter) + transpose to [b][r][v][c].
// Block = 128 threads (2 waves). Each block: 16 rows of one (b,v). Each wave:
// 8 rows x (8 columns per lane). Row values are wave-uniform LDS broadcasts
// (b128 per 4 k-steps); h reads are lane-consecutive (conflict-free).
// ---------------------------------------------------------------------------
__global__ __launch_bounds__(128) void conv_kernel(const float* __restrict__ sino,
                                                   const float* __restrict__ ws,
                                                   float* __restrict__ filt) {
    __shared__ float rows_s[16 * 512];  // 32 KiB
    __shared__ float h_s[1024];         // 4 KiB
    int t = threadIdx.x;
    int blk = blockIdx.x;               // 0..719
    int bv = blk >> 1;                  // b*180 + v
    int half = blk & 1;                 // which 16 of the 32 r's
    int b = bv / 180;
    int v = bv - b * 180;

    const float4* src4 = (const float4*)(sino + (((size_t)bv * 32) + (size_t)half * 16) * 512);
    float4* rows4 = (float4*)rows_s;
    for (int i = t; i < 2048; i += 128) rows4[i] = src4[i];
    for (int i = t; i < 1024; i += 128) h_s[i] = ws[i];
    __syncthreads();

    int wave = t >> 6;
    int lane = t & 63;
    int row0 = wave * 8;

    float acc[8][8];
#pragma unroll
    for (int j = 0; j < 8; ++j)
#pragma unroll
        for (int i = 0; i < 8; ++i) acc[j][i] = 0.f;

    for (int k = 0; k < 512; k += 4) {
        float4 rv[8];
#pragma unroll
        for (int j = 0; j < 8; ++j)
            rv[j] = *(const float4*)&rows_s[(row0 + j) * 512 + k];
#pragma unroll
        for (int u = 0; u < 4; ++u) {
            float hv[8];
            int base = lane - (k + u) + 512;   // in [1, 1023]
#pragma unroll
            for (int i = 0; i < 8; ++i) hv[i] = h_s[base + 64 * i];
#pragma unroll
            for (int j = 0; j < 8; ++j) {
                float rj = (u == 0) ? rv[j].x : (u == 1) ? rv[j].y : (u == 2) ? rv[j].z : rv[j].w;
#pragma unroll
                for (int i = 0; i < 8; ++i) acc[j][i] = fmaf(rj, hv[i], acc[j][i]);
            }
        }
    }

#pragma unroll
    for (int j = 0; j < 8; ++j) {
        int r = half * 16 + row0 + j;
        float* dst = filt + (((size_t)b * 32 + r) * 180 + v) * 512;
#pragma unroll
        for (int i = 0; i < 8; ++i) dst[lane + 64 * i] = acc[j][i];
    }
}

// ---------------------------------------------------------------------------
// Kernel C: backprojection. grid = (64 tiles, 64 slices), block = 256.
// Each block: 64x64 pixel tile of slice (b,r). Angles staged in LDS chunks of
// CH as duplicated pairs (f[c], f[c+1]) so bilinear interp = ONE ds_read_b64.
// ---------------------------------------------------------------------------
__global__ __launch_bounds__(256) void backproj_kernel(const float* __restrict__ filt,
                                                       const float* __restrict__ trig,
                                                       float* __restrict__ out) {
    __shared__ float2 pbuf[CH][512];    // 48 KiB
    int t = threadIdx.x;
    int slice = blockIdx.y;             // b*32 + r
    int tile = blockIdx.x;              // 0..63
    int x0 = (tile & 7) * 64;
    int y0 = (tile >> 3) * 64;
    int lane = t & 63;
    int yrow = t >> 6;                  // 0..3
    int px = x0 + lane;
    float xc = (float)px - 255.5f;
    float yc0 = (float)(y0 + yrow) - 255.5f;
    const float* slice_p = filt + (size_t)slice * (180 * 512);

    float acc[16];
#pragma unroll
    for (int j = 0; j < 16; ++j) acc[j] = 0.f;

    for (int chunk = 0; chunk < NCHUNK; ++chunk) {
        int v0 = chunk * CH;
        __syncthreads();   // protect previous chunk's reads
        for (int i = t; i < CH * 512; i += 256) {
            int a = i >> 9;
            int c = i & 511;
            const float* prow = slice_p + (v0 + a) * 512;
            float f0 = prow[c];
            float f1 = prow[c < 511 ? c + 1 : 511];  // pair-duplicate edge: w==0 there
            pbuf[a][c] = make_float2(f0, f1);
        }
        __syncthreads();
#pragma unroll 1
        for (int a = 0; a < CH; ++a) {
            float cth = trig[v0 + a];
            float sth = trig[180 + v0 + a];
            float tt = fmaf(yc0, sth, fmaf(xc, cth, 255.5f));
            float s4 = 4.0f * sth;
#pragma unroll
            for (int j = 0; j < 16; ++j) {
                float tc = fminf(fmaxf(tt, 0.f), 511.f);
                float fi = floorf(tc);
                float w = tc - fi;
                int i0 = (int)fi;
                float2 g = pbuf[a][i0];
                acc[j] = fmaf(w, g.y - g.x, acc[j] + g.x);
                tt += s4;
            }
        }
    }

    size_t obase = ((size_t)slice * 512 + (size_t)(y0 + yrow)) * 512 + (size_t)px;
#pragma unroll
    for (int j = 0; j < 16; ++j) {
        float vv = acc[j];              // pi/V already folded into h
        out[obase + (size_t)(4 * j) * 512] = vv > 0.f ? vv : 0.f;
    }
}

extern "C" void kernel_launch(void* const* d_in, const int* in_sizes, int n_in,
                              void* d_out, int out_size, void* d_ws, size_t ws_size,
                              hipStream_t stream) {
    const float* sino = (const float*)d_in[0];
    float* out = (float*)d_out;
    float* ws = (float*)d_ws;
    float* trig = ws + 1024;
    float* filt = ws + FILT_OFF;

    precompute_kernel<<<2, 256, 0, stream>>>(ws);
    conv_kernel<<<720, 128, 0, stream>>>(sino, ws, filt);
    backproj_kernel<<<dim3(64, 64), 256, 0, stream>>>(filt, trig, out);
}

// Round 2
// 926.783 us; speedup vs baseline: 1.3762x; 1.3762x over previous
//
#include <hip/hip_runtime.h>
#include <math.h>

#ifndef M_PI
#define M_PI 3.14159265358979323846
#endif

// Problem constants
#define BB 2
#define VV 180
#define RR 32
#define CC 512
#define NPIX 512

// backprojection tiling
#define SH 16        // strip height (rows per block)
#define CH2 6        // angles per LDS chunk
#define NCHUNK2 30   // 30 * 6 = 180
#define PADL 106     // left padding of t-range
#define PW 724       // padded width: t in [-106, 617]

// ws layout (floats): [0,1024) h_ext (h duplicated, scaled by pi/V);
//                     [1024, 1024+360) trig (cos[180], sin[180]);
//                     [2048, ...) filt transposed [b][r][v][c]
#define FILT_OFF 2048

// ---------------------------------------------------------------------------
// Kernel A: ramp-filter impulse response h[k] (scaled by pi/V) + angle tables.
// ---------------------------------------------------------------------------
__global__ void precompute_kernel(float* __restrict__ ws) {
    int j = blockIdx.x * blockDim.x + threadIdx.x;  // 0..511
    if (j < 512) {
        float s = 0.f;
        for (int m = 1; m < 512; ++m) {             // m=0 term has ramp=0
            int p = (m * j) & 511;                  // exact (m*j) mod 512
            float ang = (float)(2.0 * M_PI / 512.0) * (float)p;
            int mm = m < 512 - m ? m : 512 - m;
            float ramp = 2.0f * (float)mm * (1.0f / 512.0f);
            s += ramp * cosf(ang);
        }
        s *= (1.0f / 512.0f);
        s *= (float)(M_PI / (double)VV);            // fold backprojection scale
        ws[j] = s;
        ws[j + 512] = s;                            // h_ext[j+512] == h[j]
    }
    if (j < VV) {
        float th = (float)((double)j * M_PI / 180.0);
        ws[1024 + j] = cosf(th);
        ws[1024 + 180 + j] = sinf(th);
    }
}

// ---------------------------------------------------------------------------
// Kernel B: circular convolution (ramp filter) + transpose to [b][r][v][c].
// ---------------------------------------------------------------------------
__global__ __launch_bounds__(128) void conv_kernel(const float* __restrict__ sino,
                                                   const float* __restrict__ ws,
                                                   float* __restrict__ filt) {
    __shared__ float rows_s[16 * 512];  // 32 KiB
    __shared__ float h_s[1024];         // 4 KiB
    int t = threadIdx.x;
    int blk = blockIdx.x;               // 0..719
    int bv = blk >> 1;                  // b*180 + v
    int half = blk & 1;                 // which 16 of the 32 r's
    int b = bv / 180;
    int v = bv - b * 180;

    const float4* src4 = (const float4*)(sino + (((size_t)bv * 32) + (size_t)half * 16) * 512);
    float4* rows4 = (float4*)rows_s;
    for (int i = t; i < 2048; i += 128) rows4[i] = src4[i];
    for (int i = t; i < 1024; i += 128) h_s[i] = ws[i];
    __syncthreads();

    int wave = t >> 6;
    int lane = t & 63;
    int row0 = wave * 8;

    float acc[8][8];
#pragma unroll
    for (int j = 0; j < 8; ++j)
#pragma unroll
        for (int i = 0; i < 8; ++i) acc[j][i] = 0.f;

    for (int k = 0; k < 512; k += 4) {
        float4 rv[8];
#pragma unroll
        for (int j = 0; j < 8; ++j)
            rv[j] = *(const float4*)&rows_s[(row0 + j) * 512 + k];
#pragma unroll
        for (int u = 0; u < 4; ++u) {
            float hv[8];
            int base = lane - (k + u) + 512;   // in [1, 1023]
#pragma unroll
            for (int i = 0; i < 8; ++i) hv[i] = h_s[base + 64 * i];
#pragma unroll
            for (int j = 0; j < 8; ++j) {
                float rj = (u == 0) ? rv[j].x : (u == 1) ? rv[j].y : (u == 2) ? rv[j].z : rv[j].w;
#pragma unroll
                for (int i = 0; i < 8; ++i) acc[j][i] = fmaf(rj, hv[i], acc[j][i]);
            }
        }
    }

#pragma unroll
    for (int j = 0; j < 8; ++j) {
        int r = half * 16 + row0 + j;
        float* dst = filt + (((size_t)b * 32 + r) * 180 + v) * 512;
#pragma unroll
        for (int i = 0; i < 8; ++i) dst[lane + 64 * i] = acc[j][i];
    }
}

// ---------------------------------------------------------------------------
// Kernel C: backprojection, strip-tiled. grid = (32 strips, 64 slices),
// block = 256. Each block: 512x16 pixel strip of slice (b,r).
// LDS chunk: CH2 angles, each padded to t-range [-106,617] as (f0, d) pairs
// with edge replication (d=0 in pads) -> no clamp in inner loop; bilinear
// interp = one ds_read_b64 + v_fmac + v_add.
// ---------------------------------------------------------------------------
__global__ __launch_bounds__(256) void backproj_kernel(const float* __restrict__ filt,
                                                       const float* __restrict__ trig,
                                                       float* __restrict__ out) {
    __shared__ float2 pbuf[CH2][PW];    // 34.75 KiB
    __shared__ float trig_s[360];
    int t = threadIdx.x;
    int slice = blockIdx.y;             // b*32 + r
    int strip = blockIdx.x;             // 0..31
    int y0 = strip * SH;
    int lane = t & 63;
    int wave = t >> 6;
    int x0 = wave * 128;                // wave covers x in [x0, x0+128)
    const float* slice_p = filt + (size_t)slice * (180 * 512);

    for (int i = t; i < 360; i += 256) trig_s[i] = trig[i];

    float xc0 = (float)(x0 + lane) - 255.5f;
    float xc1 = xc0 + 64.0f;
    float yb0 = (float)y0 - 255.5f;

    float acc[2][SH];
#pragma unroll
    for (int g = 0; g < 2; ++g)
#pragma unroll
        for (int j = 0; j < SH; ++j) acc[g][j] = 0.f;

    for (int chunk = 0; chunk < NCHUNK2; ++chunk) {
        int v0 = chunk * CH2;
        __syncthreads();   // protect previous chunk's reads (also covers trig_s on chunk 0)
#pragma unroll 1
        for (int a = 0; a < CH2; ++a) {
            const float* prow = slice_p + (v0 + a) * 512;
            for (int c = t; c < PW; c += 256) {
                int s0 = c - PADL;
                int i0 = min(max(s0, 0), 511);
                int i1 = min(max(s0 + 1, 0), 511);
                float f0 = prow[i0];
                float d = prow[i1] - f0;
                pbuf[a][c] = make_float2(f0, d);
            }
        }
        __syncthreads();
#pragma unroll 1
        for (int a = 0; a < CH2; ++a) {
            float cth = trig_s[v0 + a];
            float sth = trig_s[180 + v0 + a];
            float ybase = fmaf(yb0, sth, 255.5f + (float)PADL);
            float t0 = fmaf(xc0, cth, ybase);
            float t1 = fmaf(xc1, cth, ybase);
            const float2* pr = pbuf[a];
#pragma unroll
            for (int j = 0; j < SH; ++j) {
                int i0 = (int)floorf(t0);
                float w0 = t0 - floorf(t0);
                float2 g0 = pr[i0];
                acc[0][j] = fmaf(w0, g0.y, acc[0][j]) + g0.x;
                t0 += sth;

                int i1 = (int)floorf(t1);
                float w1 = t1 - floorf(t1);
                float2 g1 = pr[i1];
                acc[1][j] = fmaf(w1, g1.y, acc[1][j]) + g1.x;
                t1 += sth;
            }
        }
    }

    size_t obase = ((size_t)slice * 512 + (size_t)y0) * 512;
#pragma unroll
    for (int j = 0; j < SH; ++j) {
        float v0o = acc[0][j];
        float v1o = acc[1][j];
        out[obase + (size_t)j * 512 + x0 + lane] = v0o > 0.f ? v0o : 0.f;
        out[obase + (size_t)j * 512 + x0 + 64 + lane] = v1o > 0.f ? v1o : 0.f;
    }
}

extern "C" void kernel_launch(void* const* d_in, const int* in_sizes, int n_in,
                              void* d_out, int out_size, void* d_ws, size_t ws_size,
                              hipStream_t stream) {
    const float* sino = (const float*)d_in[0];
    float* out = (float*)d_out;
    float* ws = (float*)d_ws;
    float* trig = ws + 1024;
    float* filt = ws + FILT_OFF;

    precompute_kernel<<<2, 256, 0, stream>>>(ws);
    conv_kernel<<<720, 128, 0, stream>>>(sino, ws, filt);
    backproj_kernel<<<dim3(32, 64), 256, 0, stream>>>(filt, trig, out);
}

// Round 3
// 900.785 us; speedup vs baseline: 1.4159x; 1.0289x over previous
//
#include <hip/hip_runtime.h>
#include <math.h>

#ifndef M_PI
#define M_PI 3.14159265358979323846
#endif

// Problem constants
#define BB 2
#define VV 180
#define RR 32
#define CC 512
#define NPIX 512

// backprojection tiling
#define SH 16        // strip height (rows per block)
#define CH2 6        // angles per LDS chunk
#define NCHUNK2 30   // 30 * 6 = 180
#define PADL 106     // left padding of t-range
#define PW 724       // padded width: t in [-106, 617]
#define TCENter 362  // recentering offset for (c,d) coefficients

// ws layout (floats): [0,1024) h_ext; [1024,1384) trig; [2048,...) filt [b][r][v][c]
#define FILT_OFF 2048

// ---------------------------------------------------------------------------
// Kernel A: ramp-filter impulse response h[k] (scaled by pi/V) + angle tables.
// ---------------------------------------------------------------------------
__global__ void precompute_kernel(float* __restrict__ ws) {
    int j = blockIdx.x * blockDim.x + threadIdx.x;  // 0..511
    if (j < 512) {
        float s = 0.f;
        for (int m = 1; m < 512; ++m) {             // m=0 term has ramp=0
            int p = (m * j) & 511;                  // exact (m*j) mod 512
            float ang = (float)(2.0 * M_PI / 512.0) * (float)p;
            int mm = m < 512 - m ? m : 512 - m;
            float ramp = 2.0f * (float)mm * (1.0f / 512.0f);
            s += ramp * cosf(ang);
        }
        s *= (1.0f / 512.0f);
        s *= (float)(M_PI / (double)VV);            // fold backprojection scale
        ws[j] = s;
        ws[j + 512] = s;                            // h_ext[j+512] == h[j]
    }
    if (j < VV) {
        float th = (float)((double)j * M_PI / 180.0);
        ws[1024 + j] = cosf(th);
        ws[1024 + 180 + j] = sinf(th);
    }
}

// ---------------------------------------------------------------------------
// Kernel B: circular convolution (ramp filter) + transpose to [b][r][v][c].
// ---------------------------------------------------------------------------
__global__ __launch_bounds__(128) void conv_kernel(const float* __restrict__ sino,
                                                   const float* __restrict__ ws,
                                                   float* __restrict__ filt) {
    __shared__ float rows_s[16 * 512];  // 32 KiB
    __shared__ float h_s[1024];         // 4 KiB
    int t = threadIdx.x;
    int blk = blockIdx.x;               // 0..719
    int bv = blk >> 1;                  // b*180 + v
    int half = blk & 1;                 // which 16 of the 32 r's
    int b = bv / 180;
    int v = bv - b * 180;

    const float4* src4 = (const float4*)(sino + (((size_t)bv * 32) + (size_t)half * 16) * 512);
    float4* rows4 = (float4*)rows_s;
    for (int i = t; i < 2048; i += 128) rows4[i] = src4[i];
    for (int i = t; i < 1024; i += 128) h_s[i] = ws[i];
    __syncthreads();

    int wave = t >> 6;
    int lane = t & 63;
    int row0 = wave * 8;

    float acc[8][8];
#pragma unroll
    for (int j = 0; j < 8; ++j)
#pragma unroll
        for (int i = 0; i < 8; ++i) acc[j][i] = 0.f;

    for (int k = 0; k < 512; k += 4) {
        float4 rv[8];
#pragma unroll
        for (int j = 0; j < 8; ++j)
            rv[j] = *(const float4*)&rows_s[(row0 + j) * 512 + k];
#pragma unroll
        for (int u = 0; u < 4; ++u) {
            float hv[8];
            int base = lane - (k + u) + 512;   // in [1, 1023]
#pragma unroll
            for (int i = 0; i < 8; ++i) hv[i] = h_s[base + 64 * i];
#pragma unroll
            for (int j = 0; j < 8; ++j) {
                float rj = (u == 0) ? rv[j].x : (u == 1) ? rv[j].y : (u == 2) ? rv[j].z : rv[j].w;
#pragma unroll
                for (int i = 0; i < 8; ++i) acc[j][i] = fmaf(rj, hv[i], acc[j][i]);
            }
        }
    }

#pragma unroll
    for (int j = 0; j < 8; ++j) {
        int r = half * 16 + row0 + j;
        float* dst = filt + (((size_t)b * 32 + r) * 180 + v) * 512;
#pragma unroll
        for (int i = 0; i < 8; ++i) dst[lane + 64 * i] = acc[j][i];
    }
}

// ---------------------------------------------------------------------------
// Kernel C: backprojection, strip-tiled. grid = (32 strips, 64 slices),
// block = 256. Each block: 512x16 pixel strip of slice (b,r).
// LDS chunk: CH2 angles, padded t-range [-106,617] stored as coefficient
// pairs (c, d) with c = f0 - (cell-362)*d, so interp value = c + t'*d with
// t' centered at 362: NO fract/w computation in the inner loop.
// Inner body: v_cvt_flr_i32_f32 + v_lshl_add + ds_read_b64 + v_fmac + 2*v_add.
// ---------------------------------------------------------------------------
__global__ __launch_bounds__(256) void backproj_kernel(const float* __restrict__ filt,
                                                       const float* __restrict__ trig,
                                                       float* __restrict__ out) {
    __shared__ float2 pbuf[CH2][PW];    // 34.75 KiB
    __shared__ float trig_s[360];
    int t = threadIdx.x;
    int slice = blockIdx.y;             // b*32 + r
    int strip = blockIdx.x;             // 0..31
    int y0 = strip * SH;
    int lane = t & 63;
    int wave = t >> 6;
    int x0 = wave * 128;                // wave covers x in [x0, x0+128)
    const float* slice_p = filt + (size_t)slice * (180 * 512);

    for (int i = t; i < 360; i += 256) trig_s[i] = trig[i];

    float xc0 = (float)(x0 + lane) - 255.5f;
    float xc1 = xc0 + 64.0f;
    float yb0 = (float)y0 - 255.5f;

    float acc[2][SH];
#pragma unroll
    for (int g = 0; g < 2; ++g)
#pragma unroll
        for (int j = 0; j < SH; ++j) acc[g][j] = 0.f;

    for (int chunk = 0; chunk < NCHUNK2; ++chunk) {
        int v0 = chunk * CH2;
        __syncthreads();   // protect previous chunk's reads (also covers trig_s on chunk 0)
#pragma unroll 1
        for (int a = 0; a < CH2; ++a) {
            const float* prow = slice_p + (v0 + a) * 512;
            for (int cx = t; cx < PW; cx += 256) {
                int s0 = cx - PADL;
                int i0 = min(max(s0, 0), 511);
                int i1 = min(max(s0 + 1, 0), 511);
                float f0 = prow[i0];
                float d = prow[i1] - f0;
                float m = (float)(cx - TCENter);
                pbuf[a][cx] = make_float2(fmaf(-m, d, f0), d);  // (c, d)
            }
        }
        __syncthreads();
#pragma unroll 1
        for (int a = 0; a < CH2; ++a) {
            float cth = trig_s[v0 + a];
            float sth = trig_s[180 + v0 + a];
            // t' = x*cth + y*sth + 255.5 + PADL - 362  in [-362, 361]
            float ybase = fmaf(yb0, sth, 255.5f + (float)PADL - (float)TCENter);
            float t0 = fmaf(xc0, cth, ybase);
            float t1 = fmaf(xc1, cth, ybase);
            const char* pb = (const char*)pbuf;
            int aoff = a * (PW * 8) + TCENter * 8;  // fold +362 back into byte addr
#pragma unroll
            for (int j = 0; j < SH; ++j) {
                int m0 = (int)floorf(t0);
                float2 g0 = *(const float2*)(pb + (m0 * 8 + aoff));
                acc[0][j] = fmaf(t0, g0.y, acc[0][j]) + g0.x;
                t0 += sth;

                int m1 = (int)floorf(t1);
                float2 g1 = *(const float2*)(pb + (m1 * 8 + aoff));
                acc[1][j] = fmaf(t1, g1.y, acc[1][j]) + g1.x;
                t1 += sth;
            }
        }
    }

    size_t obase = ((size_t)slice * 512 + (size_t)y0) * 512;
#pragma unroll
    for (int j = 0; j < SH; ++j) {
        float v0o = acc[0][j];
        float v1o = acc[1][j];
        out[obase + (size_t)j * 512 + x0 + lane] = v0o > 0.f ? v0o : 0.f;
        out[obase + (size_t)j * 512 + x0 + 64 + lane] = v1o > 0.f ? v1o : 0.f;
    }
}

extern "C" void kernel_launch(void* const* d_in, const int* in_sizes, int n_in,
                              void* d_out, int out_size, void* d_ws, size_t ws_size,
                              hipStream_t stream) {
    const float* sino = (const float*)d_in[0];
    float* out = (float*)d_out;
    float* ws = (float*)d_ws;
    float* trig = ws + 1024;
    float* filt = ws + FILT_OFF;

    precompute_kernel<<<2, 256, 0, stream>>>(ws);
    conv_kernel<<<720, 128, 0, stream>>>(sino, ws, filt);
    backproj_kernel<<<dim3(32, 64), 256, 0, stream>>>(filt, trig, out);
}

// Round 4
// 893.156 us; speedup vs baseline: 1.4280x; 1.0085x over previous
//
#include <hip/hip_runtime.h>
#include <math.h>

#ifndef M_PI
#define M_PI 3.14159265358979323846
#endif

// Problem constants
#define BB 2
#define VV 180
#define RR 32
#define CC 512
#define NPIX 512

// backprojection tiling
#define SH 16        // strip height (rows per block)
#define CH2 6        // angles per LDS chunk
#define NCHUNK2 30   // 30 * 6 = 180
#define PADL 106     // left padding of t-range
#define PW 724       // padded width: t in [-106, 617]
#define TCEN 362     // recentering offset for (c,d) coefficients

// ws layout (floats):
//   [0,1024)      h_ext (impulse response, duplicated, scaled by pi/V)
//   [1024,1384)   legacy trig: cos[180] | sin[180]        (fallback path)
//   [1408,1768)   trig2: interleaved (cos,sin) float2[180] (table path)
//   [2048,...)    table path: padded (c,d) table [64][180][724] float2 (66.7 MB)
//                 fallback path: filt [b][r][v][c] (23.6 MB)
#define TAB_OFF 2048
#define FILT_OFF 2048

// ---------------------------------------------------------------------------
// Kernel A: ramp-filter impulse response h[k] (scaled by pi/V) + angle tables.
// ---------------------------------------------------------------------------
__global__ void precompute_kernel(float* __restrict__ ws) {
    int j = blockIdx.x * blockDim.x + threadIdx.x;  // 0..511
    if (j < 512) {
        float s = 0.f;
        for (int m = 1; m < 512; ++m) {             // m=0 term has ramp=0
            int p = (m * j) & 511;                  // exact (m*j) mod 512
            float ang = (float)(2.0 * M_PI / 512.0) * (float)p;
            int mm = m < 512 - m ? m : 512 - m;
            float ramp = 2.0f * (float)mm * (1.0f / 512.0f);
            s += ramp * cosf(ang);
        }
        s *= (1.0f / 512.0f);
        s *= (float)(M_PI / (double)VV);            // fold backprojection scale
        ws[j] = s;
        ws[j + 512] = s;                            // h_ext[j+512] == h[j]
    }
    if (j < VV) {
        float th = (float)((double)j * M_PI / 180.0);
        float c = cosf(th), sn = sinf(th);
        ws[1024 + j] = c;
        ws[1024 + 180 + j] = sn;
        ws[1408 + 2 * j] = c;
        ws[1408 + 2 * j + 1] = sn;
    }
}

// ---------------------------------------------------------------------------
// Kernel B (table path): circular convolution (ramp filter) whose epilogue
// writes the PADDED coefficient table directly:
//   table[slice][v][cx] = (c, d),  cx in [0,724)
//   d = f[i1]-f[i0] (edge-clamped), c = f0 - (cx - TCEN)*d
// so backprojection interp = c + t'*d with t' centered at TCEN, and the hot
// kernel's staging is a pure copy.
// ---------------------------------------------------------------------------
__global__ __launch_bounds__(128) void conv_table_kernel(const float* __restrict__ sino,
                                                         const float* __restrict__ ws,
                                                         float* __restrict__ table) {
    __shared__ float rows_s[16 * 512];  // 32 KiB
    __shared__ float h_s[1024];         // 4 KiB
    int t = threadIdx.x;
    int blk = blockIdx.x;               // 0..719
    int bv = blk >> 1;                  // b*180 + v
    int half = blk & 1;                 // which 16 of the 32 r's
    int b = bv / 180;
    int v = bv - b * 180;

    const float4* src4 = (const float4*)(sino + (((size_t)bv * 32) + (size_t)half * 16) * 512);
    float4* rows4 = (float4*)rows_s;
    for (int i = t; i < 2048; i += 128) rows4[i] = src4[i];
    for (int i = t; i < 1024; i += 128) h_s[i] = ws[i];
    __syncthreads();

    int wave = t >> 6;
    int lane = t & 63;
    int row0 = wave * 8;

    float acc[8][8];
#pragma unroll
    for (int j = 0; j < 8; ++j)
#pragma unroll
        for (int i = 0; i < 8; ++i) acc[j][i] = 0.f;

    for (int k = 0; k < 512; k += 4) {
        float4 rv[8];
#pragma unroll
        for (int j = 0; j < 8; ++j)
            rv[j] = *(const float4*)&rows_s[(row0 + j) * 512 + k];
#pragma unroll
        for (int u = 0; u < 4; ++u) {
            float hv[8];
            int base = lane - (k + u) + 512;   // in [1, 1023]
#pragma unroll
            for (int i = 0; i < 8; ++i) hv[i] = h_s[base + 64 * i];
#pragma unroll
            for (int j = 0; j < 8; ++j) {
                float rj = (u == 0) ? rv[j].x : (u == 1) ? rv[j].y : (u == 2) ? rv[j].z : rv[j].w;
#pragma unroll
                for (int i = 0; i < 8; ++i) acc[j][i] = fmaf(rj, hv[i], acc[j][i]);
            }
        }
    }

    // Epilogue: round-trip filtered rows through LDS, emit padded (c,d) table.
    __syncthreads();   // everyone done reading rows_s / h_s
#pragma unroll
    for (int j = 0; j < 8; ++j)
#pragma unroll
        for (int i = 0; i < 8; ++i)
            rows_s[(row0 + j) * 512 + lane + 64 * i] = acc[j][i];
    __syncthreads();

    for (int jj = 0; jj < 16; ++jj) {
        const float* fr = rows_s + jj * 512;
        int slice = b * 32 + half * 16 + jj;
        float2* trow = (float2*)(table) + ((size_t)slice * 180 + v) * PW;
        for (int cx = t; cx < PW; cx += 128) {
            int s0 = cx - PADL;
            int i0 = min(max(s0, 0), 511);
            int i1 = min(max(s0 + 1, 0), 511);
            float f0 = fr[i0];
            float d = fr[i1] - f0;
            float m = (float)(cx - TCEN);
            trow[cx] = make_float2(fmaf(-m, d, f0), d);
        }
    }
}

// ---------------------------------------------------------------------------
// Kernel C (table path): backprojection. grid = (32 strips, 64 slices),
// block = 256. Staging = pure float4 copy of CH2 precomputed angle rows.
// Inner body per gather: fma(t) + cvt_flr + lshl_add + ds_read_b64 + fmac + add.
// ---------------------------------------------------------------------------
__global__ __launch_bounds__(256) void backproj2_kernel(const float* __restrict__ table,
                                                        const float2* __restrict__ trig2,
                                                        float* __restrict__ out) {
    __shared__ float2 pbuf[CH2 * PW];   // 34752 B
    __shared__ float2 trig_s[180];      // 1440 B
    int t = threadIdx.x;
    int slice = blockIdx.y;             // b*32 + r
    int strip = blockIdx.x;             // 0..31
    int y0 = strip * SH;
    int lane = t & 63;
    int wave = t >> 6;
    int x0 = wave * 128;                // wave covers x in [x0,x0+64) and [x0+64,x0+128)
    const float2* tab_slice = (const float2*)(table) + (size_t)slice * 180 * PW;

    for (int i = t; i < 180; i += 256) trig_s[i] = trig2[i];

    float xc0 = (float)(x0 + lane) - 255.5f;
    float xc1 = xc0 + 64.0f;
    float yb0 = (float)y0 - 255.5f;

    float acc[2][SH];
#pragma unroll
    for (int g = 0; g < 2; ++g)
#pragma unroll
        for (int j = 0; j < SH; ++j) acc[g][j] = 0.f;

    for (int chunk = 0; chunk < NCHUNK2; ++chunk) {
        __syncthreads();   // previous chunk's reads done (covers trig_s on chunk 0)
        const float4* src = (const float4*)(tab_slice + (size_t)chunk * (CH2 * PW));
        float4* dst = (float4*)pbuf;
        for (int i = t; i < (CH2 * PW) / 2; i += 256) dst[i] = src[i];
        __syncthreads();
#pragma unroll 1
        for (int a = 0; a < CH2; ++a) {
            float2 cs = trig_s[chunk * CH2 + a];
            int aBase = a * PW + TCEN;
            // t' = x*cos + y*sin + (255.5 + PADL - TCEN) = x*cos + y*sin - 0.5
            float t0 = fmaf(yb0, cs.y, fmaf(xc0, cs.x, -0.5f));
            float t1 = fmaf(yb0, cs.y, fmaf(xc1, cs.x, -0.5f));
#pragma unroll
            for (int j = 0; j < SH; ++j) {
                float tj0 = fmaf((float)j, cs.y, t0);
                int m0 = (int)floorf(tj0);
                float2 g0 = pbuf[aBase + m0];
                acc[0][j] = fmaf(tj0, g0.y, acc[0][j]) + g0.x;

                float tj1 = fmaf((float)j, cs.y, t1);
                int m1 = (int)floorf(tj1);
                float2 g1 = pbuf[aBase + m1];
                acc[1][j] = fmaf(tj1, g1.y, acc[1][j]) + g1.x;
            }
        }
    }

    size_t obase = ((size_t)slice * 512 + (size_t)y0) * 512;
#pragma unroll
    for (int j = 0; j < SH; ++j) {
        float v0o = acc[0][j];
        float v1o = acc[1][j];
        out[obase + (size_t)j * 512 + x0 + lane] = v0o > 0.f ? v0o : 0.f;
        out[obase + (size_t)j * 512 + x0 + 64 + lane] = v1o > 0.f ? v1o : 0.f;
    }
}

// ===========================================================================
// Fallback path (round-3 kernels) — used only if ws_size can't hold the table.
// ===========================================================================
__global__ __launch_bounds__(128) void conv_kernel(const float* __restrict__ sino,
                                                   const float* __restrict__ ws,
                                                   float* __restrict__ filt) {
    __shared__ float rows_s[16 * 512];
    __shared__ float h_s[1024];
    int t = threadIdx.x;
    int blk = blockIdx.x;
    int bv = blk >> 1;
    int half = blk & 1;
    int b = bv / 180;
    int v = bv - b * 180;

    const float4* src4 = (const float4*)(sino + (((size_t)bv * 32) + (size_t)half * 16) * 512);
    float4* rows4 = (float4*)rows_s;
    for (int i = t; i < 2048; i += 128) rows4[i] = src4[i];
    for (int i = t; i < 1024; i += 128) h_s[i] = ws[i];
    __syncthreads();

    int wave = t >> 6;
    int lane = t & 63;
    int row0 = wave * 8;

    float acc[8][8];
#pragma unroll
    for (int j = 0; j < 8; ++j)
#pragma unroll
        for (int i = 0; i < 8; ++i) acc[j][i] = 0.f;

    for (int k = 0; k < 512; k += 4) {
        float4 rv[8];
#pragma unroll
        for (int j = 0; j < 8; ++j)
            rv[j] = *(const float4*)&rows_s[(row0 + j) * 512 + k];
#pragma unroll
        for (int u = 0; u < 4; ++u) {
            float hv[8];
            int base = lane - (k + u) + 512;
#pragma unroll
            for (int i = 0; i < 8; ++i) hv[i] = h_s[base + 64 * i];
#pragma unroll
            for (int j = 0; j < 8; ++j) {
                float rj = (u == 0) ? rv[j].x : (u == 1) ? rv[j].y : (u == 2) ? rv[j].z : rv[j].w;
#pragma unroll
                for (int i = 0; i < 8; ++i) acc[j][i] = fmaf(rj, hv[i], acc[j][i]);
            }
        }
    }

#pragma unroll
    for (int j = 0; j < 8; ++j) {
        int r = half * 16 + row0 + j;
        float* dst = filt + (((size_t)b * 32 + r) * 180 + v) * 512;
#pragma unroll
        for (int i = 0; i < 8; ++i) dst[lane + 64 * i] = acc[j][i];
    }
}

__global__ __launch_bounds__(256) void backproj_kernel(const float* __restrict__ filt,
                                                       const float* __restrict__ trig,
                                                       float* __restrict__ out) {
    __shared__ float2 pbuf[CH2][PW];
    __shared__ float trig_s[360];
    int t = threadIdx.x;
    int slice = blockIdx.y;
    int strip = blockIdx.x;
    int y0 = strip * SH;
    int lane = t & 63;
    int wave = t >> 6;
    int x0 = wave * 128;
    const float* slice_p = filt + (size_t)slice * (180 * 512);

    for (int i = t; i < 360; i += 256) trig_s[i] = trig[i];

    float xc0 = (float)(x0 + lane) - 255.5f;
    float xc1 = xc0 + 64.0f;
    float yb0 = (float)y0 - 255.5f;

    float acc[2][SH];
#pragma unroll
    for (int g = 0; g < 2; ++g)
#pragma unroll
        for (int j = 0; j < SH; ++j) acc[g][j] = 0.f;

    for (int chunk = 0; chunk < NCHUNK2; ++chunk) {
        int v0 = chunk * CH2;
        __syncthreads();
#pragma unroll 1
        for (int a = 0; a < CH2; ++a) {
            const float* prow = slice_p + (v0 + a) * 512;
            for (int cx = t; cx < PW; cx += 256) {
                int s0 = cx - PADL;
                int i0 = min(max(s0, 0), 511);
                int i1 = min(max(s0 + 1, 0), 511);
                float f0 = prow[i0];
                float d = prow[i1] - f0;
                float m = (float)(cx - TCEN);
                pbuf[a][cx] = make_float2(fmaf(-m, d, f0), d);
            }
        }
        __syncthreads();
#pragma unroll 1
        for (int a = 0; a < CH2; ++a) {
            float cth = trig_s[v0 + a];
            float sth = trig_s[180 + v0 + a];
            float ybase = fmaf(yb0, sth, 255.5f + (float)PADL - (float)TCEN);
            float t0 = fmaf(xc0, cth, ybase);
            float t1 = fmaf(xc1, cth, ybase);
            const char* pb = (const char*)pbuf;
            int aoff = a * (PW * 8) + TCEN * 8;
#pragma unroll
            for (int j = 0; j < SH; ++j) {
                int m0 = (int)floorf(t0);
                float2 g0 = *(const float2*)(pb + (m0 * 8 + aoff));
                acc[0][j] = fmaf(t0, g0.y, acc[0][j]) + g0.x;
                t0 += sth;

                int m1 = (int)floorf(t1);
                float2 g1 = *(const float2*)(pb + (m1 * 8 + aoff));
                acc[1][j] = fmaf(t1, g1.y, acc[1][j]) + g1.x;
                t1 += sth;
            }
        }
    }

    size_t obase = ((size_t)slice * 512 + (size_t)y0) * 512;
#pragma unroll
    for (int j = 0; j < SH; ++j) {
        float v0o = acc[0][j];
        float v1o = acc[1][j];
        out[obase + (size_t)j * 512 + x0 + lane] = v0o > 0.f ? v0o : 0.f;
        out[obase + (size_t)j * 512 + x0 + 64 + lane] = v1o > 0.f ? v1o : 0.f;
    }
}

extern "C" void kernel_launch(void* const* d_in, const int* in_sizes, int n_in,
                              void* d_out, int out_size, void* d_ws, size_t ws_size,
                              hipStream_t stream) {
    const float* sino = (const float*)d_in[0];
    float* out = (float*)d_out;
    float* ws = (float*)d_ws;

    size_t tableFloats = (size_t)64 * 180 * PW * 2;         // 16.68M floats
    size_t neededA = (TAB_OFF + tableFloats) * sizeof(float);  // ~66.7 MB

    precompute_kernel<<<2, 256, 0, stream>>>(ws);
    if (ws_size >= neededA) {
        float* table = ws + TAB_OFF;
        conv_table_kernel<<<720, 128, 0, stream>>>(sino, ws, table);
        backproj2_kernel<<<dim3(32, 64), 256, 0, stream>>>(table, (const float2*)(ws + 1408), out);
    } else {
        float* filt = ws + FILT_OFF;
        conv_kernel<<<720, 128, 0, stream>>>(sino, ws, filt);
        backproj_kernel<<<dim3(32, 64), 256, 0, stream>>>(filt, ws + 1024, out);
    }
}

// Round 5
// 685.967 us; speedup vs baseline: 1.8593x; 1.3020x over previous
//
#include <hip/hip_runtime.h>
#include <math.h>

#ifndef M_PI
#define M_PI 3.14159265358979323846
#endif

// Problem constants
#define BB 2
#define VV 180
#define RR 32
#define CC 512
#define NPIX 512

#define PADL 106     // left padding of t-range
#define PW 724       // padded width: t_real in [-106, 617]
#define TCEN 362     // recentering offset for (c,d) coefficients

// pair-orbit backprojection tiling
#define SH3 8        // rep-rows per block
#define CHP 2        // angle-PAIRS per LDS chunk
#define NCHP 45      // 45 * 2 = 90 pairs = 180 angles

// fallback tiling (round-3 kernels)
#define SH 16
#define CH2 6
#define NCHUNK2 30

// ws layout (floats):
//   [0,1024)      h_ext (impulse response, duplicated, scaled by pi/V)
//   [1024,1384)   legacy trig: cos[180] | sin[180]          (fallback path)
//   [1408,1768)   trig2: interleaved (cos,sin) float2[180]  (pair path uses first 90)
//   [2048,...)    pair path: table [64 slices][90 pairs][724] float4 = 66.7 MB
//                 fallback:  filt [b][r][v][c] = 23.6 MB
#define TAB_OFF 2048
#define FILT_OFF 2048

// ---------------------------------------------------------------------------
// Kernel A: ramp-filter impulse response h[k] (scaled by pi/V) + angle tables.
// ---------------------------------------------------------------------------
__global__ void precompute_kernel(float* __restrict__ ws) {
    int j = blockIdx.x * blockDim.x + threadIdx.x;  // 0..511
    if (j < 512) {
        float s = 0.f;
        for (int m = 1; m < 512; ++m) {             // m=0 term has ramp=0
            int p = (m * j) & 511;                  // exact (m*j) mod 512
            float ang = (float)(2.0 * M_PI / 512.0) * (float)p;
            int mm = m < 512 - m ? m : 512 - m;
            float ramp = 2.0f * (float)mm * (1.0f / 512.0f);
            s += ramp * cosf(ang);
        }
        s *= (1.0f / 512.0f);
        s *= (float)(M_PI / (double)VV);            // fold backprojection scale
        ws[j] = s;
        ws[j + 512] = s;                            // h_ext[j+512] == h[j]
    }
    if (j < VV) {
        float th = (float)((double)j * M_PI / 180.0);
        float c = cosf(th), sn = sinf(th);
        ws[1024 + j] = c;
        ws[1024 + 180 + j] = sn;
        ws[1408 + 2 * j] = c;
        ws[1408 + 2 * j + 1] = sn;
    }
}

// ---------------------------------------------------------------------------
// Kernel B (pair path): ramp-filter convolution; epilogue writes the padded
// coefficient table in PAIRED layout:
//   tab4[slice][p][cx] = (c_p, d_p, c_{p+90}, d_{p+90}),  p in [0,90)
// Each conv block handles one angle v and writes its (c,d) into the .xy or
// .zw half (strided 8-of-16B stores).
// ---------------------------------------------------------------------------
__global__ __launch_bounds__(128) void conv_table_kernel(const float* __restrict__ sino,
                                                         const float* __restrict__ ws,
                                                         float* __restrict__ table) {
    __shared__ float rows_s[16 * 512];  // 32 KiB
    __shared__ float h_s[1024];         // 4 KiB
    int t = threadIdx.x;
    int blk = blockIdx.x;               // 0..719
    int bv = blk >> 1;                  // b*180 + v
    int half = blk & 1;                 // which 16 of the 32 r's
    int b = bv / 180;
    int v = bv - b * 180;

    const float4* src4 = (const float4*)(sino + (((size_t)bv * 32) + (size_t)half * 16) * 512);
    float4* rows4 = (float4*)rows_s;
    for (int i = t; i < 2048; i += 128) rows4[i] = src4[i];
    for (int i = t; i < 1024; i += 128) h_s[i] = ws[i];
    __syncthreads();

    int wave = t >> 6;
    int lane = t & 63;
    int row0 = wave * 8;

    float acc[8][8];
#pragma unroll
    for (int j = 0; j < 8; ++j)
#pragma unroll
        for (int i = 0; i < 8; ++i) acc[j][i] = 0.f;

    for (int k = 0; k < 512; k += 4) {
        float4 rv[8];
#pragma unroll
        for (int j = 0; j < 8; ++j)
            rv[j] = *(const float4*)&rows_s[(row0 + j) * 512 + k];
#pragma unroll
        for (int u = 0; u < 4; ++u) {
            float hv[8];
            int base = lane - (k + u) + 512;   // in [1, 1023]
#pragma unroll
            for (int i = 0; i < 8; ++i) hv[i] = h_s[base + 64 * i];
#pragma unroll
            for (int j = 0; j < 8; ++j) {
                float rj = (u == 0) ? rv[j].x : (u == 1) ? rv[j].y : (u == 2) ? rv[j].z : rv[j].w;
#pragma unroll
                for (int i = 0; i < 8; ++i) acc[j][i] = fmaf(rj, hv[i], acc[j][i]);
            }
        }
    }

    // Epilogue: round-trip filtered rows through LDS, emit padded (c,d) halves.
    __syncthreads();
#pragma unroll
    for (int j = 0; j < 8; ++j)
#pragma unroll
        for (int i = 0; i < 8; ++i)
            rows_s[(row0 + j) * 512 + lane + 64 * i] = acc[j][i];
    __syncthreads();

    int p = (v < 90) ? v : v - 90;
    size_t halfByte = (v < 90) ? 0 : 8;
    for (int jj = 0; jj < 16; ++jj) {
        const float* fr = rows_s + jj * 512;
        int slice = b * 32 + half * 16 + jj;
        char* trow = (char*)table + (((size_t)slice * 90 + p) * PW) * 16 + halfByte;
        for (int cx = t; cx < PW; cx += 128) {
            int s0 = cx - PADL;
            int i0 = min(max(s0, 0), 511);
            int i1 = min(max(s0 + 1, 0), 511);
            float f0 = fr[i0];
            float d = fr[i1] - f0;
            float m = (float)(cx - TCEN);
            *(float2*)(trow + (size_t)cx * 16) = make_float2(fmaf(-m, d, f0), d);
        }
    }
}

// ---------------------------------------------------------------------------
// Kernel C (pair path): orbit backprojection. grid = (32 strips, 64 slices),
// block = 256 (one lane = one 4-pixel 90-degree-rotation orbit, reps in the
// [256,512)^2 quadrant). Angle pairs (v, v+90): orbit sample positions are
// {a,-a,b,-b} shared between the two angles, so each ds_read_b128 of
// (c_v,d_v,c_w,d_w) serves TWO pixel-angle samples.
// ---------------------------------------------------------------------------
__global__ __launch_bounds__(256, 6) void backproj_pair_kernel(const float4* __restrict__ tab,
                                                               const float2* __restrict__ trigp,
                                                               float* __restrict__ out) {
    __shared__ float4 pbuf[CHP * PW];   // 23168 B -> 6 blocks/CU
    __shared__ float2 trig_s[90];
    int t = threadIdx.x;
    int slice = blockIdx.y;             // b*32 + r
    int strip = blockIdx.x;             // 0..31
    int y0 = strip * SH3;               // rep-row offset in [0,256)
    const float4* tslice = tab + (size_t)slice * (90 * PW);

    for (int i = t; i < 90; i += 256) trig_s[i] = trigp[i];

    float xc = (float)t + 0.5f;         // rep px = 256+t  ->  xc = px-255.5

    float acc0[SH3], acc1[SH3], acc2[SH3], acc3[SH3];
#pragma unroll
    for (int j = 0; j < SH3; ++j) { acc0[j] = 0.f; acc1[j] = 0.f; acc2[j] = 0.f; acc3[j] = 0.f; }

    for (int chunk = 0; chunk < NCHP; ++chunk) {
        __syncthreads();                // previous chunk consumed (covers trig_s on chunk 0)
        const float4* src = tslice + chunk * (CHP * PW);
        for (int i = t; i < CHP * PW; i += 256) pbuf[i] = src[i];
        __syncthreads();
#pragma unroll
        for (int pa = 0; pa < CHP; ++pa) {
            float2 cs = trig_s[chunk * CHP + pa];
            const float4* pb = pbuf + pa * PW + TCEN;
#pragma unroll
            for (int j = 0; j < SH3; ++j) {
                float ycj = (float)(y0 + j) + 0.5f;
                float ysm  = fmaf(ycj, cs.y, -0.5f);    // y*sin - 0.5
                float yccm = fmaf(-ycj, cs.x, -0.5f);   // -y*cos - 0.5
                float ua  = fmaf(xc, cs.x, ysm);        // u( a) = x c + y s - .5
                float ub  = fmaf(xc, cs.y, yccm);       // u( b) = x s - y c - .5
                float uma = -1.0f - ua;                 // u(-a)
                float umb = -1.0f - ub;                 // u(-b)
                int ma  = (int)floorf(ua);
                int mma = (int)floorf(uma);
                int mb  = (int)floorf(ub);
                int mmb = (int)floorf(umb);
                float4 qa  = pb[ma];
                float4 qma = pb[mma];
                float4 qb  = pb[mb];
                float4 qmb = pb[mmb];
                acc0[j] = fmaf(ua,  qa.y,  acc0[j]) + qa.x;    // P0 @ v
                acc1[j] = fmaf(ua,  qa.w,  acc1[j]) + qa.z;    // P1 @ v+90
                acc2[j] = fmaf(uma, qma.y, acc2[j]) + qma.x;   // P2 @ v
                acc3[j] = fmaf(uma, qma.w, acc3[j]) + qma.z;   // P3 @ v+90
                acc1[j] = fmaf(ub,  qb.y,  acc1[j]) + qb.x;    // P1 @ v
                acc2[j] = fmaf(ub,  qb.w,  acc2[j]) + qb.z;    // P2 @ v+90
                acc3[j] = fmaf(umb, qmb.y, acc3[j]) + qmb.x;   // P3 @ v
                acc0[j] = fmaf(umb, qmb.w, acc0[j]) + qmb.z;   // P0 @ v+90
            }
        }
    }

    // Orbit writes. P0/P2 are row-coalesced; P1/P3 are per-lane 32B row
    // segments (columns of the orbit) - accepted write amplification.
    int px = 256 + t;
    size_t sbase = (size_t)slice * (512 * 512);
#pragma unroll
    for (int j = 0; j < SH3; ++j) {
        int py = 256 + y0 + j;
        float v0 = acc0[j], v1 = acc1[j], v2 = acc2[j], v3 = acc3[j];
        out[sbase + (size_t)py * 512 + px]                   = v0 > 0.f ? v0 : 0.f;  // (x=px,    y=py)
        out[sbase + (size_t)px * 512 + (511 - py)]           = v1 > 0.f ? v1 : 0.f;  // (x=511-py,y=px)
        out[sbase + (size_t)(511 - py) * 512 + (511 - px)]   = v2 > 0.f ? v2 : 0.f;  // (x=511-px,y=511-py)
        out[sbase + (size_t)(511 - px) * 512 + py]           = v3 > 0.f ? v3 : 0.f;  // (x=py,    y=511-px)
    }
}

// ===========================================================================
// Fallback path (round-3 kernels) - used only if ws_size can't hold the table.
// ===========================================================================
__global__ __launch_bounds__(128) void conv_kernel(const float* __restrict__ sino,
                                                   const float* __restrict__ ws,
                                                   float* __restrict__ filt) {
    __shared__ float rows_s[16 * 512];
    __shared__ float h_s[1024];
    int t = threadIdx.x;
    int blk = blockIdx.x;
    int bv = blk >> 1;
    int half = blk & 1;
    int b = bv / 180;
    int v = bv - b * 180;

    const float4* src4 = (const float4*)(sino + (((size_t)bv * 32) + (size_t)half * 16) * 512);
    float4* rows4 = (float4*)rows_s;
    for (int i = t; i < 2048; i += 128) rows4[i] = src4[i];
    for (int i = t; i < 1024; i += 128) h_s[i] = ws[i];
    __syncthreads();

    int wave = t >> 6;
    int lane = t & 63;
    int row0 = wave * 8;

    float acc[8][8];
#pragma unroll
    for (int j = 0; j < 8; ++j)
#pragma unroll
        for (int i = 0; i < 8; ++i) acc[j][i] = 0.f;

    for (int k = 0; k < 512; k += 4) {
        float4 rv[8];
#pragma unroll
        for (int j = 0; j < 8; ++j)
            rv[j] = *(const float4*)&rows_s[(row0 + j) * 512 + k];
#pragma unroll
        for (int u = 0; u < 4; ++u) {
            float hv[8];
            int base = lane - (k + u) + 512;
#pragma unroll
            for (int i = 0; i < 8; ++i) hv[i] = h_s[base + 64 * i];
#pragma unroll
            for (int j = 0; j < 8; ++j) {
                float rj = (u == 0) ? rv[j].x : (u == 1) ? rv[j].y : (u == 2) ? rv[j].z : rv[j].w;
#pragma unroll
                for (int i = 0; i < 8; ++i) acc[j][i] = fmaf(rj, hv[i], acc[j][i]);
            }
        }
    }

#pragma unroll
    for (int j = 0; j < 8; ++j) {
        int r = half * 16 + row0 + j;
        float* dst = filt + (((size_t)b * 32 + r) * 180 + v) * 512;
#pragma unroll
        for (int i = 0; i < 8; ++i) dst[lane + 64 * i] = acc[j][i];
    }
}

__global__ __launch_bounds__(256) void backproj_kernel(const float* __restrict__ filt,
                                                       const float* __restrict__ trig,
                                                       float* __restrict__ out) {
    __shared__ float2 pbuf[CH2][PW];
    __shared__ float trig_s[360];
    int t = threadIdx.x;
    int slice = blockIdx.y;
    int strip = blockIdx.x;
    int y0 = strip * SH;
    int lane = t & 63;
    int wave = t >> 6;
    int x0 = wave * 128;
    const float* slice_p = filt + (size_t)slice * (180 * 512);

    for (int i = t; i < 360; i += 256) trig_s[i] = trig[i];

    float xc0 = (float)(x0 + lane) - 255.5f;
    float xc1 = xc0 + 64.0f;
    float yb0 = (float)y0 - 255.5f;

    float acc[2][SH];
#pragma unroll
    for (int g = 0; g < 2; ++g)
#pragma unroll
        for (int j = 0; j < SH; ++j) acc[g][j] = 0.f;

    for (int chunk = 0; chunk < NCHUNK2; ++chunk) {
        int v0 = chunk * CH2;
        __syncthreads();
#pragma unroll 1
        for (int a = 0; a < CH2; ++a) {
            const float* prow = slice_p + (v0 + a) * 512;
            for (int cx = t; cx < PW; cx += 256) {
                int s0 = cx - PADL;
                int i0 = min(max(s0, 0), 511);
                int i1 = min(max(s0 + 1, 0), 511);
                float f0 = prow[i0];
                float d = prow[i1] - f0;
                float m = (float)(cx - TCEN);
                pbuf[a][cx] = make_float2(fmaf(-m, d, f0), d);
            }
        }
        __syncthreads();
#pragma unroll 1
        for (int a = 0; a < CH2; ++a) {
            float cth = trig_s[v0 + a];
            float sth = trig_s[180 + v0 + a];
            float ybase = fmaf(yb0, sth, 255.5f + (float)PADL - (float)TCEN);
            float t0 = fmaf(xc0, cth, ybase);
            float t1 = fmaf(xc1, cth, ybase);
            const char* pb = (const char*)pbuf;
            int aoff = a * (PW * 8) + TCEN * 8;
#pragma unroll
            for (int j = 0; j < SH; ++j) {
                int m0 = (int)floorf(t0);
                float2 g0 = *(const float2*)(pb + (m0 * 8 + aoff));
                acc[0][j] = fmaf(t0, g0.y, acc[0][j]) + g0.x;
                t0 += sth;

                int m1 = (int)floorf(t1);
                float2 g1 = *(const float2*)(pb + (m1 * 8 + aoff));
                acc[1][j] = fmaf(t1, g1.y, acc[1][j]) + g1.x;
                t1 += sth;
            }
        }
    }

    size_t obase = ((size_t)slice * 512 + (size_t)y0) * 512;
#pragma unroll
    for (int j = 0; j < SH; ++j) {
        float v0o = acc[0][j];
        float v1o = acc[1][j];
        out[obase + (size_t)j * 512 + x0 + lane] = v0o > 0.f ? v0o : 0.f;
        out[obase + (size_t)j * 512 + x0 + 64 + lane] = v1o > 0.f ? v1o : 0.f;
    }
}

extern "C" void kernel_launch(void* const* d_in, const int* in_sizes, int n_in,
                              void* d_out, int out_size, void* d_ws, size_t ws_size,
                              hipStream_t stream) {
    const float* sino = (const float*)d_in[0];
    float* out = (float*)d_out;
    float* ws = (float*)d_ws;

    size_t tableFloats = (size_t)64 * 90 * PW * 4;             // 16.68M floats
    size_t needed = (TAB_OFF + tableFloats) * sizeof(float);   // ~66.7 MB

    precompute_kernel<<<2, 256, 0, stream>>>(ws);
    if (ws_size >= needed) {
        float* table = ws + TAB_OFF;
        conv_table_kernel<<<720, 128, 0, stream>>>(sino, ws, table);
        backproj_pair_kernel<<<dim3(32, 64), 256, 0, stream>>>((const float4*)table,
                                                               (const float2*)(ws + 1408), out);
    } else {
        float* filt = ws + FILT_OFF;
        conv_kernel<<<720, 128, 0, stream>>>(sino, ws, filt);
        backproj_kernel<<<dim3(32, 64), 256, 0, stream>>>(filt, ws + 1024, out);
    }
}